// Round 13
// baseline (110.604 us; speedup 1.0000x reference)
//
#include <hip/hip_runtime.h>

// ---------------------------------------------------------------------------
// QueryInteractionModuleGroup2 — round 12: R11 base (best=109.7) +
//  * k_gemmln: 512 threads / 8 waves (wave owns 32 cols) — double TLP for
//    the B-load latency chain (was 1 block/CU x 4 waves, latency-bound)
// 8 launches. N=4096, D=256, H=8, HD=32, FF=1024, groups=4
// ---------------------------------------------------------------------------

typedef __attribute__((ext_vector_type(8))) __bf16 bf16x8;
typedef __attribute__((ext_vector_type(4))) float f32x4;

#define NSPLIT 4

static __device__ __forceinline__ unsigned short f2bf(float f) {
    union { float f; unsigned u; } v; v.f = f;
    unsigned r = v.u + 0x7fffu + ((v.u >> 16) & 1u);
    return (unsigned short)(r >> 16);
}

// async global->LDS, 16B per lane; LDS dest = wave-uniform base + lane*16
static __device__ __forceinline__ void gload16(const unsigned short* g, unsigned short* l) {
    __builtin_amdgcn_global_load_lds(
        (const __attribute__((address_space(1))) unsigned int*)g,
        (__attribute__((address_space(3))) unsigned int*)l, 16, 0, 0);
}

// ---------------------------------------------------------------------------
// Mega-setup: blocks 0..319 convert weights f32->bf16; block 320 sorts;
// blocks 321..1344 do prep (UNSORTED row space — no rank dependency).
// ---------------------------------------------------------------------------
__global__ __launch_bounds__(1024) void k_setup(
    const float* __restrict__ w0, const float* __restrict__ w1,
    const float* __restrict__ w2, const float* __restrict__ w3,
    const float* __restrict__ w4, const float* __restrict__ w5,
    unsigned short* __restrict__ o0, unsigned short* __restrict__ o1,
    unsigned short* __restrict__ o2, unsigned short* __restrict__ o3,
    unsigned short* __restrict__ o4, unsigned short* __restrict__ o5,
    const int* __restrict__ gid, int N,
    int* __restrict__ perm, int* __restrict__ gid_s, int* __restrict__ offs,
    const float* __restrict__ ref_pts, const float* __restrict__ pred_boxes,
    const float* __restrict__ scores, const float* __restrict__ embed,
    unsigned short* __restrict__ qk_bf, unsigned short* __restrict__ emb_bf)
{
    int bid = blockIdx.x, tid = threadIdx.x;
    if (bid < 320) {
        long i = ((long)bid * 1024 + tid) * 4;
        const float* src; unsigned short* dst; long off;
        if      (i <  196608) { src = w0; dst = o0; off = i; }
        else if (i <  262144) { src = w1; dst = o1; off = i -  196608; }
        else if (i <  524288) { src = w2; dst = o2; off = i -  262144; }
        else if (i <  786432) { src = w3; dst = o3; off = i -  524288; }
        else if (i < 1048576) { src = w4; dst = o4; off = i -  786432; }
        else                  { src = w5; dst = o5; off = i - 1048576; }
        float4 v = *(const float4*)(src + off);
        ushort4 o; o.x = f2bf(v.x); o.y = f2bf(v.y); o.z = f2bf(v.z); o.w = f2bf(v.w);
        *(ushort4*)(dst + off) = o;
        return;
    }
    if (bid == 320) {
        __shared__ int cnt[1024][4];
        __shared__ int base[4];
        int t = tid;
        int per = N / 1024;
        int c[4] = {0, 0, 0, 0};
        for (int i = 0; i < per; ++i) c[gid[t * per + i] & 3]++;
        for (int g = 0; g < 4; ++g) cnt[t][g] = c[g];
        __syncthreads();
        for (int off = 1; off < 1024; off <<= 1) {
            int v[4] = {0, 0, 0, 0};
            if (t >= off) for (int g = 0; g < 4; ++g) v[g] = cnt[t - off][g];
            __syncthreads();
            if (t >= off) for (int g = 0; g < 4; ++g) cnt[t][g] += v[g];
            __syncthreads();
        }
        if (t == 0) {
            base[0] = 0;
            base[1] = cnt[1023][0];
            base[2] = base[1] + cnt[1023][1];
            base[3] = base[2] + cnt[1023][2];
            offs[0] = 0; offs[1] = base[1]; offs[2] = base[2]; offs[3] = base[3]; offs[4] = N;
        }
        __syncthreads();
        int run[4];
        for (int g = 0; g < 4; ++g) run[g] = base[g] + (t ? cnt[t - 1][g] : 0);
        for (int i = 0; i < per; ++i) {
            int n = t * per + i;
            int g = gid[n] & 3;
            int p = run[g]++;
            perm[p] = n; gid_s[p] = g;
        }
        return;
    }
    // prep (UNSORTED): n = (bid-321)*4 + tid>>8, d = tid&255
    int n = (bid - 321) * 4 + (tid >> 8), d = tid & 255;
    bool ip = scores[n] > 0.5f;
    int c = d >> 6, k = (d >> 1) & 31, s = d & 1;
    float p = (ip ? pred_boxes : ref_pts)[n * 4 + c] * 6.283185307179586f;
    float freq = exp2f(-(float)k * (13.287712379549449f / 32.0f));
    float ang = p * freq;
    float e = s ? cosf(ang) : sinf(ang);
    float em = embed[(size_t)n * 256 + d];
    qk_bf[(size_t)n * 256 + d] = f2bf(e + em);
    emb_bf[(size_t)n * 256 + d] = f2bf(em);
}

// ---------------------------------------------------------------------------
// GEMM (64x64 tile, BK=64, double-buffered, global_load_lds staging).
// (unchanged from R11 — proven)
// ---------------------------------------------------------------------------
#define EPI_QKV     0
#define EPI_RELUBF  3

template<int EPI>
__global__ __launch_bounds__(256) void k_gemm(
    const unsigned short* __restrict__ A, const unsigned short* __restrict__ A2,
    const unsigned short* __restrict__ B,
    const float* __restrict__ bias, const int* __restrict__ perm,
    void* __restrict__ out, void* __restrict__ out2,
    int M, int Nout, int K)
{
    __shared__ __align__(16) unsigned short As[2][64][64];
    __shared__ __align__(16) unsigned short Bs[2][64][64];
    int mt = M >> 6;
    int bm = blockIdx.x % mt, bn = blockIdx.x / mt;
    int m0 = bm * 64, c0 = bn * 64;
    int tid = threadIdx.x;
    int wave = tid >> 6, lane = tid & 63;
    int wr = wave >> 1, wc = wave & 1;
    int g = lane >> 4, r15 = lane & 15;

    const unsigned short* Asrc = A;
    if constexpr (EPI == EPI_QKV) { if (c0 >= 512) Asrc = A2; }

    int rl0 = wave * 16 + (lane >> 3);
    int rl1 = rl0 + 8;
    int cch = lane & 7;
    int sc0 = (cch ^ (rl0 & 7)) * 8;
    int sc1 = (cch ^ (rl1 & 7)) * 8;
    int gra0 = m0 + rl0, gra1 = m0 + rl1;
    if constexpr (EPI == EPI_QKV) { gra0 = perm[m0 + rl0]; gra1 = perm[m0 + rl1]; }
    const unsigned short* Ap0 = Asrc + (size_t)gra0 * K + sc0;
    const unsigned short* Ap1 = Asrc + (size_t)gra1 * K + sc1;
    const unsigned short* Bp0 = B + (size_t)(c0 + rl0) * K + sc0;
    const unsigned short* Bp1 = B + (size_t)(c0 + rl1) * K + sc1;
    int wb0 = wave * 16, wb1 = wave * 16 + 8;

    gload16(Ap0, &As[0][wb0][0]);
    gload16(Ap1, &As[0][wb1][0]);
    gload16(Bp0, &Bs[0][wb0][0]);
    gload16(Bp1, &Bs[0][wb1][0]);
    __syncthreads();

    f32x4 acc[2][2] = {};
    int nk = K >> 6;
    for (int kt = 0; kt < nk; ++kt) {
        int cur = kt & 1;
        if (kt + 1 < nk) {
            int ko = (kt + 1) << 6;
            gload16(Ap0 + ko, &As[cur ^ 1][wb0][0]);
            gload16(Ap1 + ko, &As[cur ^ 1][wb1][0]);
            gload16(Bp0 + ko, &Bs[cur ^ 1][wb0][0]);
            gload16(Bp1 + ko, &Bs[cur ^ 1][wb1][0]);
        }
        #pragma unroll
        for (int kk = 0; kk < 2; ++kk) {
            int ra0 = wr * 32 + r15, ra1 = wr * 32 + 16 + r15;
            int rb0 = wc * 32 + r15, rb1 = wc * 32 + 16 + r15;
            int cu = kk * 4 + g;
            bf16x8 af0 = *(const bf16x8*)(&As[cur][ra0][(cu ^ (ra0 & 7)) * 8]);
            bf16x8 af1 = *(const bf16x8*)(&As[cur][ra1][(cu ^ (ra1 & 7)) * 8]);
            bf16x8 bf0 = *(const bf16x8*)(&Bs[cur][rb0][(cu ^ (rb0 & 7)) * 8]);
            bf16x8 bf1 = *(const bf16x8*)(&Bs[cur][rb1][(cu ^ (rb1 & 7)) * 8]);
            acc[0][0] = __builtin_amdgcn_mfma_f32_16x16x32_bf16(af0, bf0, acc[0][0], 0, 0, 0);
            acc[0][1] = __builtin_amdgcn_mfma_f32_16x16x32_bf16(af0, bf1, acc[0][1], 0, 0, 0);
            acc[1][0] = __builtin_amdgcn_mfma_f32_16x16x32_bf16(af1, bf0, acc[1][0], 0, 0, 0);
            acc[1][1] = __builtin_amdgcn_mfma_f32_16x16x32_bf16(af1, bf1, acc[1][1], 0, 0, 0);
        }
        __syncthreads();
    }

    #pragma unroll
    for (int ti = 0; ti < 2; ++ti)
    #pragma unroll
    for (int tj = 0; tj < 2; ++tj)
    #pragma unroll
    for (int r = 0; r < 4; ++r) {
        int n = m0 + wr * 32 + ti * 16 + g * 4 + r;
        int o = c0 + wc * 32 + tj * 16 + r15;
        float v = acc[ti][tj][r] + bias[o];
        if constexpr (EPI == EPI_QKV) {
            if (o < 512) {
                float s = (o < 256) ? (0.17677669529663687f * 1.4426950408889634f) : 1.0f;
                ((unsigned short*)out)[(size_t)n * 512 + o] = f2bf(v * s);
            } else {
                ((unsigned short*)out2)[(size_t)(o - 512) * M + n] = f2bf(v);
            }
        } else {
            ((unsigned short*)out)[(size_t)n * Nout + o] = f2bf(fmaxf(v, 0.0f));
        }
    }
}

// ---------------------------------------------------------------------------
// Fused GEMM (Nout=256) + LayerNorm. grid = N/16, block = 512 (8 waves);
// wave owns 32 cols x 16 rows (acc[2], 4 B-loads + 4 MFMA per K-step).
// MODE 0: A = combine(Opart x NSPLIT), resid out_embed[perm], LN1 -> tgtf+tgtbf
// MODE 1: A = hbuf, resid tgtf (sorted), LN2 -> t2bf
// MODE 2: A = hbuf, resid query_pos[perm], LNf -> select+scatter f32 d_out
// ---------------------------------------------------------------------------
template<int K, int MODE>
__global__ __launch_bounds__(512) void k_gemmln(
    const unsigned short* __restrict__ Abf,
    const float* __restrict__ Opart, const float* __restrict__ lpart,
    const unsigned short* __restrict__ Bw,
    const float* __restrict__ bias, const float* __restrict__ resid,
    const float* __restrict__ lnw, const float* __restrict__ lnb,
    float* __restrict__ outf32, unsigned short* __restrict__ outbf,
    const float* __restrict__ scores, const int* __restrict__ perm, int N)
{
    __shared__ __align__(16) unsigned short As[2][16][72];
    __shared__ float sW[8][16];
    __shared__ float qW[8][16];
    __shared__ float mS[16], rS[16];
    __shared__ int pm[16];

    const int m0 = blockIdx.x * 16;
    const int tid = threadIdx.x, wave = tid >> 6, lane = tid & 63;
    const int g = lane >> 4, r15 = lane & 15;
    const int ar = tid >> 3, au = tid & 7;
    const bool stager = (tid < 128);

    if (tid < 16) pm[tid] = (MODE == 1) ? (m0 + tid) : perm[m0 + tid];

    auto loadA = [&](int kt) -> uint4 {
        int n = m0 + ar;
        int c = kt * 64 + au * 8;
        if constexpr (MODE == 0) {
            int h = c >> 5;
            float lsum = 0.f;
            #pragma unroll
            for (int s = 0; s < NSPLIT; ++s)
                lsum += lpart[((size_t)s * N + n) * 8 + h];
            float inv = 1.0f / lsum;
            float o8[8] = {};
            #pragma unroll
            for (int s = 0; s < NSPLIT; ++s) {
                const float* p = Opart + ((size_t)s * N + n) * 256 + c;
                float4 x0 = *(const float4*)(p);
                float4 x1 = *(const float4*)(p + 4);
                o8[0] += x0.x; o8[1] += x0.y; o8[2] += x0.z; o8[3] += x0.w;
                o8[4] += x1.x; o8[5] += x1.y; o8[6] += x1.z; o8[7] += x1.w;
            }
            uint4 o;
            o.x = f2bf(o8[0] * inv) | ((unsigned)f2bf(o8[1] * inv) << 16);
            o.y = f2bf(o8[2] * inv) | ((unsigned)f2bf(o8[3] * inv) << 16);
            o.z = f2bf(o8[4] * inv) | ((unsigned)f2bf(o8[5] * inv) << 16);
            o.w = f2bf(o8[6] * inv) | ((unsigned)f2bf(o8[7] * inv) << 16);
            return o;
        } else {
            return *(const uint4*)(Abf + (size_t)n * K + c);
        }
    };

    // B fragment base: output col = wave*32 + tj*16 + r15, chunk col g*8
    const unsigned short* Bb = Bw + (size_t)(wave * 32 + r15) * K + g * 8;
#define LOADB(dst, kt, kk, tj) dst = *(const bf16x8*)(Bb + (size_t)(tj) * 16 * K + (kt) * 64 + (kk) * 32)

    bf16x8 c00, c01, c10, c11;
    uint4 pa;
    if (stager) { pa = loadA(0); *(uint4*)(&As[0][ar][au * 8]) = pa; }
    LOADB(c00, 0, 0, 0); LOADB(c01, 0, 0, 1);
    LOADB(c10, 0, 1, 0); LOADB(c11, 0, 1, 1);
    __syncthreads();

    f32x4 acc[2] = {};
    constexpr int nk = K >> 6;
    #pragma unroll
    for (int kt = 0; kt < nk; ++kt) {
        int cur = kt & 1;
        bool more = (kt + 1 < nk);
        bf16x8 n00, n01, n10, n11;
        if (more) {
            if (stager) pa = loadA(kt + 1);
            LOADB(n00, kt + 1, 0, 0); LOADB(n01, kt + 1, 0, 1);
            LOADB(n10, kt + 1, 1, 0); LOADB(n11, kt + 1, 1, 1);
        }
        bf16x8 af0 = *(const bf16x8*)(&As[cur][r15][g * 8]);
        acc[0] = __builtin_amdgcn_mfma_f32_16x16x32_bf16(af0, c00, acc[0], 0, 0, 0);
        acc[1] = __builtin_amdgcn_mfma_f32_16x16x32_bf16(af0, c01, acc[1], 0, 0, 0);
        bf16x8 af1 = *(const bf16x8*)(&As[cur][r15][32 + g * 8]);
        acc[0] = __builtin_amdgcn_mfma_f32_16x16x32_bf16(af1, c10, acc[0], 0, 0, 0);
        acc[1] = __builtin_amdgcn_mfma_f32_16x16x32_bf16(af1, c11, acc[1], 0, 0, 0);
        if (more) {
            if (stager) *(uint4*)(&As[cur ^ 1][ar][au * 8]) = pa;
            __syncthreads();
            c00 = n00; c01 = n01; c10 = n10; c11 = n11;
        }
    }
#undef LOADB

    float vals[2][4];
    float vs[4] = {0.f, 0.f, 0.f, 0.f}, vq[4] = {0.f, 0.f, 0.f, 0.f};
    #pragma unroll
    for (int tj = 0; tj < 2; ++tj) {
        int col = wave * 32 + tj * 16 + r15;
        float b = bias[col];
        #pragma unroll
        for (int r = 0; r < 4; ++r) {
            int row = g * 4 + r;
            float v = acc[tj][r] + b + resid[(size_t)pm[row] * 256 + col];
            vals[tj][r] = v;
            vs[r] += v; vq[r] += v * v;
        }
    }
    #pragma unroll
    for (int off = 1; off < 16; off <<= 1)
        #pragma unroll
        for (int r = 0; r < 4; ++r) {
            vs[r] += __shfl_xor(vs[r], off, 64);
            vq[r] += __shfl_xor(vq[r], off, 64);
        }
    if (r15 == 0) {
        #pragma unroll
        for (int r = 0; r < 4; ++r) { sW[wave][g * 4 + r] = vs[r]; qW[wave][g * 4 + r] = vq[r]; }
    }
    __syncthreads();
    if (tid < 16) {
        float s = 0.f, q = 0.f;
        #pragma unroll
        for (int w = 0; w < 8; ++w) { s += sW[w][tid]; q += qW[w][tid]; }
        float mean = s * (1.0f / 256.0f);
        float var = q * (1.0f / 256.0f) - mean * mean;
        mS[tid] = mean;
        rS[tid] = rsqrtf(fmaxf(var, 0.f) + 1e-5f);
    }
    __syncthreads();

    #pragma unroll
    for (int tj = 0; tj < 2; ++tj) {
        int col = wave * 32 + tj * 16 + r15;
        float w = lnw[col], bb = lnb[col];
        #pragma unroll
        for (int r = 0; r < 4; ++r) {
            int row = g * 4 + r;
            float o = (vals[tj][r] - mS[row]) * rS[row] * w + bb;
            if constexpr (MODE == 0) {
                outf32[(size_t)(m0 + row) * 256 + col] = o;
                outbf[(size_t)(m0 + row) * 256 + col] = f2bf(o);
            } else if constexpr (MODE == 1) {
                outbf[(size_t)(m0 + row) * 256 + col] = f2bf(o);
            } else {
                int no = pm[row];
                bool ip = scores[no] > 0.5f;
                float qp = resid[(size_t)no * 256 + col];
                outf32[(size_t)no * 256 + col] = ip ? o : qp;
            }
        }
    }
}

// ---------------------------------------------------------------------------
// Group-sorted masked flash attention, swapped QK^T, max-free exp2 softmax.
// Key-split NSPLIT=4. (unchanged — proven)
// ---------------------------------------------------------------------------
__global__ __launch_bounds__(256) void k_attn(
    const unsigned short* __restrict__ QK, const unsigned short* __restrict__ Vt,
    const int* __restrict__ gid_s, const int* __restrict__ offs,
    float* __restrict__ Opart, float* __restrict__ lpart, int N)
{
    __shared__ __align__(16) unsigned short Ks[2][64][40];
    __shared__ __align__(16) unsigned short Vs[2][32][72];
    __shared__ __align__(16) unsigned short Ps[4][16][64];
    __shared__ __align__(16) int gks[2][64];

    int qtiles = N >> 6;
    int bid = blockIdx.x;
    int qt = bid % qtiles;
    int hs = bid / qtiles;
    int h = hs & 7;
    int sp = hs >> 3;
    int q0 = qt * 64;
    int tid = threadIdx.x, wave = tid >> 6, lane = tid & 63;
    int g = lane >> 4, r15 = lane & 15;
    int n0 = q0 + wave * 16;

    int g_lo = gid_s[q0], g_hi = gid_s[q0 + 63];
    int tlo = offs[g_lo] >> 6;
    int thi = (offs[g_hi + 1] + 63) >> 6;
    int ntiles = thi - tlo;
    int chunk = (ntiles + NSPLIT - 1) / NSPLIT;
    int t0 = tlo + sp * chunk;
    int t1 = min(t0 + chunk, thi);

    if (t0 >= t1) {
        #pragma unroll
        for (int r = 0; r < 4; ++r) {
            int n = n0 + g * 4 + r;
            Opart[((size_t)sp * N + n) * 256 + h * 32 + r15] = 0.f;
            Opart[((size_t)sp * N + n) * 256 + h * 32 + 16 + r15] = 0.f;
        }
        if (g == 0) lpart[((size_t)sp * N + n0 + r15) * 8 + h] = 0.f;
        return;
    }

    bf16x8 qf = *(const bf16x8*)(QK + (size_t)(n0 + r15) * 512 + h * 32 + g * 8);
    int gq = gid_s[n0 + r15];

    int kr_ = tid >> 2, kc_ = (tid & 3) * 8;
    int vd_ = tid >> 3, vc_ = (tid & 7) * 8;

    f32x4 O0 = {}, O1 = {};
    float lloc = 0.f;
    unsigned short* PsW = &Ps[wave][0][0];

    {
        int m0 = t0 << 6;
        *(uint4*)(&Ks[0][kr_][kc_]) = *(const uint4*)(QK + (size_t)(m0 + kr_) * 512 + 256 + h * 32 + kc_);
        *(uint4*)(&Vs[0][vd_][vc_]) = *(const uint4*)(Vt + (size_t)(h * 32 + vd_) * N + m0 + vc_);
        if (tid < 64) gks[0][tid] = gid_s[m0 + tid];
    }
    __syncthreads();

    int cur = 0;
    for (int t = t0; t < t1; ++t) {
        bool more = (t + 1 < t1);
        uint4 kn, vn; int gn = 0;
        if (more) {
            int m0n = (t + 1) << 6;
            kn = *(const uint4*)(QK + (size_t)(m0n + kr_) * 512 + 256 + h * 32 + kc_);
            vn = *(const uint4*)(Vt + (size_t)(h * 32 + vd_) * N + m0n + vc_);
            if (tid < 64) gn = gid_s[m0n + tid];
        }

        f32x4 S[4];
        #pragma unroll
        for (int t_ = 0; t_ < 4; ++t_) {
            bf16x8 kf = *(const bf16x8*)(&Ks[cur][t_ * 16 + r15][g * 8]);
            f32x4 z = {};
            S[t_] = __builtin_amdgcn_mfma_f32_16x16x32_bf16(kf, qf, z, 0, 0, 0);
        }
        #pragma unroll
        for (int t_ = 0; t_ < 4; ++t_) {
            int4 g4 = *(const int4*)(&gks[cur][t_ * 16 + g * 4]);
            float p0 = (g4.x == gq) ? exp2f(S[t_][0]) : 0.f;
            float p1 = (g4.y == gq) ? exp2f(S[t_][1]) : 0.f;
            float p2 = (g4.z == gq) ? exp2f(S[t_][2]) : 0.f;
            float p3 = (g4.w == gq) ? exp2f(S[t_][3]) : 0.f;
            lloc += (p0 + p1) + (p2 + p3);
            ushort4 pw;
            pw.x = f2bf(p0); pw.y = f2bf(p1); pw.z = f2bf(p2); pw.w = f2bf(p3);
            int off = t_ * 32 + g * 8;
            int byte = r15 * 128 + ((((off >> 4) ^ (r15 & 7)) << 4) | (off & 15));
            *(ushort4*)((char*)PsW + byte) = pw;
        }
        #pragma unroll
        for (int kk = 0; kk < 2; ++kk) {
            int byte = r15 * 128 + (((kk * 4 + g) ^ (r15 & 7)) << 4);
            bf16x8 pf = *(const bf16x8*)((char*)PsW + byte);
            bf16x8 v0 = *(const bf16x8*)(&Vs[cur][r15][kk * 32 + g * 8]);
            bf16x8 v1 = *(const bf16x8*)(&Vs[cur][16 + r15][kk * 32 + g * 8]);
            O0 = __builtin_amdgcn_mfma_f32_16x16x32_bf16(pf, v0, O0, 0, 0, 0);
            O1 = __builtin_amdgcn_mfma_f32_16x16x32_bf16(pf, v1, O1, 0, 0, 0);
        }

        if (more) {
            *(uint4*)(&Ks[cur ^ 1][kr_][kc_]) = kn;
            *(uint4*)(&Vs[cur ^ 1][vd_][vc_]) = vn;
            if (tid < 64) gks[cur ^ 1][tid] = gn;
        }
        __syncthreads();
        cur ^= 1;
    }

    float l = lloc;
    l += __shfl_xor(l, 16, 64);
    l += __shfl_xor(l, 32, 64);
    if (g == 0) lpart[((size_t)sp * N + n0 + r15) * 8 + h] = l;

    #pragma unroll
    for (int r = 0; r < 4; ++r) {
        int n = n0 + g * 4 + r;
        Opart[((size_t)sp * N + n) * 256 + h * 32 + r15]      = O0[r];
        Opart[((size_t)sp * N + n) * 256 + h * 32 + 16 + r15] = O1[r];
    }
}

// ---------------------------------------------------------------------------
extern "C" void kernel_launch(void* const* d_in, const int* in_sizes, int n_in,
                              void* d_out, int out_size, void* d_ws, size_t ws_size,
                              hipStream_t stream)
{
    const float* ref_pts    = (const float*)d_in[0];
    const float* pred_boxes = (const float*)d_in[1];
    const float* scores     = (const float*)d_in[2];
    const float* out_embed  = (const float*)d_in[3];
    const float* query_pos  = (const float*)d_in[4];
    const int*   group_ids  = (const int*)d_in[5];
    const float* in_proj_w  = (const float*)d_in[7];
    const float* in_proj_b  = (const float*)d_in[8];
    const float* out_proj_w = (const float*)d_in[9];
    const float* out_proj_b = (const float*)d_in[10];
    const float* lin1_w     = (const float*)d_in[11];
    const float* lin1_b     = (const float*)d_in[12];
    const float* lin2_w     = (const float*)d_in[13];
    const float* lin2_b     = (const float*)d_in[14];
    const float* feat1_w    = (const float*)d_in[15];
    const float* feat1_b    = (const float*)d_in[16];
    const float* feat2_w    = (const float*)d_in[17];
    const float* feat2_b    = (const float*)d_in[18];
    const float* norm1_w    = (const float*)d_in[19];
    const float* norm1_b    = (const float*)d_in[20];
    const float* norm2_w    = (const float*)d_in[21];
    const float* norm2_b    = (const float*)d_in[22];
    const float* normf_w    = (const float*)d_in[23];
    const float* normf_b    = (const float*)d_in[24];

    const int N = in_sizes[2];  // 4096

    char* ws = (char*)d_ws;
    size_t off = 0;
    auto alloc = [&](size_t bytes) -> void* {
        void* p = ws + off; off += (bytes + 255) & ~(size_t)255; return p;
    };
    unsigned short* wqkv   = (unsigned short*)alloc((size_t)768 * 256 * 2);
    unsigned short* wout   = (unsigned short*)alloc((size_t)256 * 256 * 2);
    unsigned short* wlin1  = (unsigned short*)alloc((size_t)1024 * 256 * 2);
    unsigned short* wlin2  = (unsigned short*)alloc((size_t)256 * 1024 * 2);
    unsigned short* wfeat1 = (unsigned short*)alloc((size_t)1024 * 256 * 2);
    unsigned short* wfeat2 = (unsigned short*)alloc((size_t)256 * 1024 * 2);
    unsigned short* qk_bf  = (unsigned short*)alloc((size_t)N * 256 * 2);
    unsigned short* emb_bf = (unsigned short*)alloc((size_t)N * 256 * 2);
    unsigned short* QKbuf  = (unsigned short*)alloc((size_t)N * 512 * 2);
    unsigned short* Vtbuf  = (unsigned short*)alloc((size_t)256 * N * 2);
    float*          tgtf   = (float*)alloc((size_t)N * 256 * 4);
    unsigned short* tgtbf  = (unsigned short*)alloc((size_t)N * 256 * 2);
    unsigned short* t2bf   = (unsigned short*)alloc((size_t)N * 256 * 2);
    unsigned short* hbuf   = (unsigned short*)alloc((size_t)N * 1024 * 2);
    int* permbuf = (int*)alloc((size_t)N * 4);
    int* gidsbuf = (int*)alloc((size_t)N * 4);
    int* offsbuf = (int*)alloc(32 * 4);
    float* Opartbuf = (float*)alloc((size_t)NSPLIT * N * 256 * 4);
    float* lbuf     = (float*)alloc((size_t)NSPLIT * N * 8 * 4);
    (void)ws_size; (void)n_in; (void)out_size;

    const int mt = N >> 6;

    // 1: weight conversion || group sort || prep (unsorted)
    k_setup<<<1345, 1024, 0, stream>>>(in_proj_w, out_proj_w, lin1_w, lin2_w, feat1_w, feat2_w,
                                       wqkv, wout, wlin1, wlin2, wfeat1, wfeat2,
                                       group_ids, N, permbuf, gidsbuf, offsbuf,
                                       ref_pts, pred_boxes, scores, out_embed,
                                       qk_bf, emb_bf);
    // 2: fused QKV projection (gathers A-rows via perm -> sorted outputs)
    k_gemm<EPI_QKV><<<mt * 12, 256, 0, stream>>>(
        qk_bf, emb_bf, wqkv, in_proj_b, permbuf, QKbuf, Vtbuf, N, 768, 256);
    // 3: key-split swapped-QK^T flash attention (NSPLIT=4)
    k_attn<<<mt * 8 * NSPLIT, 256, 0, stream>>>(QKbuf, Vtbuf, gidsbuf, offsbuf,
                                                Opartbuf, lbuf, N);
    // 4: out-proj (+combine, +residual out_embed[perm], +LN1) -> tgtf, tgtbf
    k_gemmln<256, 0><<<N / 16, 512, 0, stream>>>(
        nullptr, Opartbuf, lbuf, wout, out_proj_b, out_embed,
        norm1_w, norm1_b, tgtf, tgtbf, nullptr, permbuf, N);
    // 5: lin1 + relu -> hbuf
    k_gemm<EPI_RELUBF><<<mt * 16, 256, 0, stream>>>(
        tgtbf, nullptr, wlin1, lin1_b, nullptr, hbuf, nullptr, N, 1024, 256);
    // 6: lin2 (+residual tgtf, +LN2) -> t2bf
    k_gemmln<1024, 1><<<N / 16, 512, 0, stream>>>(
        hbuf, nullptr, nullptr, wlin2, lin2_b, tgtf,
        norm2_w, norm2_b, nullptr, t2bf, nullptr, permbuf, N);
    // 7: feat1 + relu -> hbuf
    k_gemm<EPI_RELUBF><<<mt * 16, 256, 0, stream>>>(
        t2bf, nullptr, wfeat1, feat1_b, nullptr, hbuf, nullptr, N, 1024, 256);
    // 8: feat2 (+residual query_pos[perm], +LNf, +select, +scatter) -> d_out
    k_gemmln<1024, 2><<<N / 16, 512, 0, stream>>>(
        hbuf, nullptr, nullptr, wfeat2, feat2_b, query_pos,
        normf_w, normf_b, (float*)d_out, nullptr, scores, permbuf, N);
}

// Round 14
// 109.611 us; speedup vs baseline: 1.0091x; 1.0091x over previous
//
#include <hip/hip_runtime.h>

// ---------------------------------------------------------------------------
// QueryInteractionModuleGroup2 — round 13: FINAL — revert to R11 (measured
// best, 109.7 µs). R12's 8-wave gemmln was null; banking the proven config.
// 8 launches. N=4096, D=256, H=8, HD=32, FF=1024, groups=4
// Session: 211.5 -> 109.7 µs. Key wins: group-sort (4x attn FLOP cut),
// swapped-QK^T max-free softmax, key-split, BK=64 dbuf GEMM, fused epilogues,
// merged setup, global_load_lds staging.
// ---------------------------------------------------------------------------

typedef __attribute__((ext_vector_type(8))) __bf16 bf16x8;
typedef __attribute__((ext_vector_type(4))) float f32x4;

#define NSPLIT 4

static __device__ __forceinline__ unsigned short f2bf(float f) {
    union { float f; unsigned u; } v; v.f = f;
    unsigned r = v.u + 0x7fffu + ((v.u >> 16) & 1u);
    return (unsigned short)(r >> 16);
}

// async global->LDS, 16B per lane; LDS dest = wave-uniform base + lane*16
static __device__ __forceinline__ void gload16(const unsigned short* g, unsigned short* l) {
    __builtin_amdgcn_global_load_lds(
        (const __attribute__((address_space(1))) unsigned int*)g,
        (__attribute__((address_space(3))) unsigned int*)l, 16, 0, 0);
}

// ---------------------------------------------------------------------------
// Mega-setup: blocks 0..319 convert weights f32->bf16; block 320 sorts;
// blocks 321..1344 do prep (UNSORTED row space — no rank dependency).
// ---------------------------------------------------------------------------
__global__ __launch_bounds__(1024) void k_setup(
    const float* __restrict__ w0, const float* __restrict__ w1,
    const float* __restrict__ w2, const float* __restrict__ w3,
    const float* __restrict__ w4, const float* __restrict__ w5,
    unsigned short* __restrict__ o0, unsigned short* __restrict__ o1,
    unsigned short* __restrict__ o2, unsigned short* __restrict__ o3,
    unsigned short* __restrict__ o4, unsigned short* __restrict__ o5,
    const int* __restrict__ gid, int N,
    int* __restrict__ perm, int* __restrict__ gid_s, int* __restrict__ offs,
    const float* __restrict__ ref_pts, const float* __restrict__ pred_boxes,
    const float* __restrict__ scores, const float* __restrict__ embed,
    unsigned short* __restrict__ qk_bf, unsigned short* __restrict__ emb_bf)
{
    int bid = blockIdx.x, tid = threadIdx.x;
    if (bid < 320) {
        long i = ((long)bid * 1024 + tid) * 4;
        const float* src; unsigned short* dst; long off;
        if      (i <  196608) { src = w0; dst = o0; off = i; }
        else if (i <  262144) { src = w1; dst = o1; off = i -  196608; }
        else if (i <  524288) { src = w2; dst = o2; off = i -  262144; }
        else if (i <  786432) { src = w3; dst = o3; off = i -  524288; }
        else if (i < 1048576) { src = w4; dst = o4; off = i -  786432; }
        else                  { src = w5; dst = o5; off = i - 1048576; }
        float4 v = *(const float4*)(src + off);
        ushort4 o; o.x = f2bf(v.x); o.y = f2bf(v.y); o.z = f2bf(v.z); o.w = f2bf(v.w);
        *(ushort4*)(dst + off) = o;
        return;
    }
    if (bid == 320) {
        __shared__ int cnt[1024][4];
        __shared__ int base[4];
        int t = tid;
        int per = N / 1024;
        int c[4] = {0, 0, 0, 0};
        for (int i = 0; i < per; ++i) c[gid[t * per + i] & 3]++;
        for (int g = 0; g < 4; ++g) cnt[t][g] = c[g];
        __syncthreads();
        for (int off = 1; off < 1024; off <<= 1) {
            int v[4] = {0, 0, 0, 0};
            if (t >= off) for (int g = 0; g < 4; ++g) v[g] = cnt[t - off][g];
            __syncthreads();
            if (t >= off) for (int g = 0; g < 4; ++g) cnt[t][g] += v[g];
            __syncthreads();
        }
        if (t == 0) {
            base[0] = 0;
            base[1] = cnt[1023][0];
            base[2] = base[1] + cnt[1023][1];
            base[3] = base[2] + cnt[1023][2];
            offs[0] = 0; offs[1] = base[1]; offs[2] = base[2]; offs[3] = base[3]; offs[4] = N;
        }
        __syncthreads();
        int run[4];
        for (int g = 0; g < 4; ++g) run[g] = base[g] + (t ? cnt[t - 1][g] : 0);
        for (int i = 0; i < per; ++i) {
            int n = t * per + i;
            int g = gid[n] & 3;
            int p = run[g]++;
            perm[p] = n; gid_s[p] = g;
        }
        return;
    }
    // prep (UNSORTED): n = (bid-321)*4 + tid>>8, d = tid&255
    int n = (bid - 321) * 4 + (tid >> 8), d = tid & 255;
    bool ip = scores[n] > 0.5f;
    int c = d >> 6, k = (d >> 1) & 31, s = d & 1;
    float p = (ip ? pred_boxes : ref_pts)[n * 4 + c] * 6.283185307179586f;
    float freq = exp2f(-(float)k * (13.287712379549449f / 32.0f));
    float ang = p * freq;
    float e = s ? cosf(ang) : sinf(ang);
    float em = embed[(size_t)n * 256 + d];
    qk_bf[(size_t)n * 256 + d] = f2bf(e + em);
    emb_bf[(size_t)n * 256 + d] = f2bf(em);
}

// ---------------------------------------------------------------------------
// GEMM (64x64 tile, BK=64, double-buffered, global_load_lds staging).
// LDS layout: unpadded [64][64] shorts; LDS(r, chunk u) holds global chunk
// u^(r&7) (source pre-swizzled); reads use chunk (kk*4+g)^(row&7) -> 2-way
// bank aliasing (free). Per wave: rows [16w,16w+16) via two 8-row 1KB calls.
// EPI_QKV: A-rows gathered via perm; c0<512 -> QKbuf (Q scaled), else Vt^T.
// EPI_RELUBF: out bf16 = relu(acc + bias).
// ---------------------------------------------------------------------------
#define EPI_QKV     0
#define EPI_RELUBF  3

template<int EPI>
__global__ __launch_bounds__(256) void k_gemm(
    const unsigned short* __restrict__ A, const unsigned short* __restrict__ A2,
    const unsigned short* __restrict__ B,
    const float* __restrict__ bias, const int* __restrict__ perm,
    void* __restrict__ out, void* __restrict__ out2,
    int M, int Nout, int K)
{
    __shared__ __align__(16) unsigned short As[2][64][64];
    __shared__ __align__(16) unsigned short Bs[2][64][64];
    int mt = M >> 6;
    int bm = blockIdx.x % mt, bn = blockIdx.x / mt;
    int m0 = bm * 64, c0 = bn * 64;
    int tid = threadIdx.x;
    int wave = tid >> 6, lane = tid & 63;
    int wr = wave >> 1, wc = wave & 1;
    int g = lane >> 4, r15 = lane & 15;

    const unsigned short* Asrc = A;
    if constexpr (EPI == EPI_QKV) { if (c0 >= 512) Asrc = A2; }

    // staging: wave stages rows [wave*16, wave*16+16) of A and B tiles.
    int rl0 = wave * 16 + (lane >> 3);
    int rl1 = rl0 + 8;
    int cch = lane & 7;
    int sc0 = (cch ^ (rl0 & 7)) * 8;
    int sc1 = (cch ^ (rl1 & 7)) * 8;
    int gra0 = m0 + rl0, gra1 = m0 + rl1;
    if constexpr (EPI == EPI_QKV) { gra0 = perm[m0 + rl0]; gra1 = perm[m0 + rl1]; }
    const unsigned short* Ap0 = Asrc + (size_t)gra0 * K + sc0;
    const unsigned short* Ap1 = Asrc + (size_t)gra1 * K + sc1;
    const unsigned short* Bp0 = B + (size_t)(c0 + rl0) * K + sc0;
    const unsigned short* Bp1 = B + (size_t)(c0 + rl1) * K + sc1;
    int wb0 = wave * 16, wb1 = wave * 16 + 8;

    gload16(Ap0, &As[0][wb0][0]);
    gload16(Ap1, &As[0][wb1][0]);
    gload16(Bp0, &Bs[0][wb0][0]);
    gload16(Bp1, &Bs[0][wb1][0]);
    __syncthreads();

    f32x4 acc[2][2] = {};
    int nk = K >> 6;
    for (int kt = 0; kt < nk; ++kt) {
        int cur = kt & 1;
        if (kt + 1 < nk) {
            int ko = (kt + 1) << 6;
            gload16(Ap0 + ko, &As[cur ^ 1][wb0][0]);
            gload16(Ap1 + ko, &As[cur ^ 1][wb1][0]);
            gload16(Bp0 + ko, &Bs[cur ^ 1][wb0][0]);
            gload16(Bp1 + ko, &Bs[cur ^ 1][wb1][0]);
        }
        #pragma unroll
        for (int kk = 0; kk < 2; ++kk) {
            int ra0 = wr * 32 + r15, ra1 = wr * 32 + 16 + r15;
            int rb0 = wc * 32 + r15, rb1 = wc * 32 + 16 + r15;
            int cu = kk * 4 + g;
            bf16x8 af0 = *(const bf16x8*)(&As[cur][ra0][(cu ^ (ra0 & 7)) * 8]);
            bf16x8 af1 = *(const bf16x8*)(&As[cur][ra1][(cu ^ (ra1 & 7)) * 8]);
            bf16x8 bf0 = *(const bf16x8*)(&Bs[cur][rb0][(cu ^ (rb0 & 7)) * 8]);
            bf16x8 bf1 = *(const bf16x8*)(&Bs[cur][rb1][(cu ^ (rb1 & 7)) * 8]);
            acc[0][0] = __builtin_amdgcn_mfma_f32_16x16x32_bf16(af0, bf0, acc[0][0], 0, 0, 0);
            acc[0][1] = __builtin_amdgcn_mfma_f32_16x16x32_bf16(af0, bf1, acc[0][1], 0, 0, 0);
            acc[1][0] = __builtin_amdgcn_mfma_f32_16x16x32_bf16(af1, bf0, acc[1][0], 0, 0, 0);
            acc[1][1] = __builtin_amdgcn_mfma_f32_16x16x32_bf16(af1, bf1, acc[1][1], 0, 0, 0);
        }
        __syncthreads();
    }

    #pragma unroll
    for (int ti = 0; ti < 2; ++ti)
    #pragma unroll
    for (int tj = 0; tj < 2; ++tj)
    #pragma unroll
    for (int r = 0; r < 4; ++r) {
        int n = m0 + wr * 32 + ti * 16 + g * 4 + r;
        int o = c0 + wc * 32 + tj * 16 + r15;
        float v = acc[ti][tj][r] + bias[o];
        if constexpr (EPI == EPI_QKV) {
            if (o < 512) {
                float s = (o < 256) ? (0.17677669529663687f * 1.4426950408889634f) : 1.0f;
                ((unsigned short*)out)[(size_t)n * 512 + o] = f2bf(v * s);
            } else {
                ((unsigned short*)out2)[(size_t)(o - 512) * M + n] = f2bf(v);
            }
        } else {
            ((unsigned short*)out)[(size_t)n * Nout + o] = f2bf(fmaxf(v, 0.0f));
        }
    }
}

// ---------------------------------------------------------------------------
// Fused GEMM (Nout=256) + LayerNorm. grid = N/16, 4 waves. (proven R9/R11)
// MODE 0: A = combine(Opart x NSPLIT), resid out_embed[perm], LN1 -> tgtf+tgtbf
// MODE 1: A = hbuf, resid tgtf (sorted), LN2 -> t2bf
// MODE 2: A = hbuf, resid query_pos[perm], LNf -> select+scatter f32 d_out
// ---------------------------------------------------------------------------
template<int K, int MODE>
__global__ __launch_bounds__(256) void k_gemmln(
    const unsigned short* __restrict__ Abf,
    const float* __restrict__ Opart, const float* __restrict__ lpart,
    const unsigned short* __restrict__ Bw,
    const float* __restrict__ bias, const float* __restrict__ resid,
    const float* __restrict__ lnw, const float* __restrict__ lnb,
    float* __restrict__ outf32, unsigned short* __restrict__ outbf,
    const float* __restrict__ scores, const int* __restrict__ perm, int N)
{
    __shared__ __align__(16) unsigned short As[2][16][72];
    __shared__ float sW[4][16];
    __shared__ float qW[4][16];
    __shared__ float mS[16], rS[16];
    __shared__ int pm[16];

    const int m0 = blockIdx.x * 16;
    const int tid = threadIdx.x, wave = tid >> 6, lane = tid & 63;
    const int g = lane >> 4, r15 = lane & 15;
    const int ar = tid >> 3, au = tid & 7;
    const bool stager = (tid < 128);

    if (tid < 16) pm[tid] = (MODE == 1) ? (m0 + tid) : perm[m0 + tid];

    auto loadA = [&](int kt) -> uint4 {
        int n = m0 + ar;
        int c = kt * 64 + au * 8;
        if constexpr (MODE == 0) {
            int h = c >> 5;
            float lsum = 0.f;
            #pragma unroll
            for (int s = 0; s < NSPLIT; ++s)
                lsum += lpart[((size_t)s * N + n) * 8 + h];
            float inv = 1.0f / lsum;
            float o8[8] = {};
            #pragma unroll
            for (int s = 0; s < NSPLIT; ++s) {
                const float* p = Opart + ((size_t)s * N + n) * 256 + c;
                float4 x0 = *(const float4*)(p);
                float4 x1 = *(const float4*)(p + 4);
                o8[0] += x0.x; o8[1] += x0.y; o8[2] += x0.z; o8[3] += x0.w;
                o8[4] += x1.x; o8[5] += x1.y; o8[6] += x1.z; o8[7] += x1.w;
            }
            uint4 o;
            o.x = f2bf(o8[0] * inv) | ((unsigned)f2bf(o8[1] * inv) << 16);
            o.y = f2bf(o8[2] * inv) | ((unsigned)f2bf(o8[3] * inv) << 16);
            o.z = f2bf(o8[4] * inv) | ((unsigned)f2bf(o8[5] * inv) << 16);
            o.w = f2bf(o8[6] * inv) | ((unsigned)f2bf(o8[7] * inv) << 16);
            return o;
        } else {
            return *(const uint4*)(Abf + (size_t)n * K + c);
        }
    };

    const unsigned short* Bb = Bw + (size_t)(wave * 64 + r15) * K + g * 8;
#define LOADB(dst, kt, kk, tj) dst = *(const bf16x8*)(Bb + (size_t)(tj) * 16 * K + (kt) * 64 + (kk) * 32)

    bf16x8 c00, c01, c02, c03, c10, c11, c12, c13;
    uint4 pa;
    if (stager) { pa = loadA(0); *(uint4*)(&As[0][ar][au * 8]) = pa; }
    LOADB(c00, 0, 0, 0); LOADB(c01, 0, 0, 1); LOADB(c02, 0, 0, 2); LOADB(c03, 0, 0, 3);
    LOADB(c10, 0, 1, 0); LOADB(c11, 0, 1, 1); LOADB(c12, 0, 1, 2); LOADB(c13, 0, 1, 3);
    __syncthreads();

    f32x4 acc[4] = {};
    constexpr int nk = K >> 6;
    #pragma unroll
    for (int kt = 0; kt < nk; ++kt) {
        int cur = kt & 1;
        bool more = (kt + 1 < nk);
        bf16x8 n00, n01, n02, n03, n10, n11, n12, n13;
        if (more) {
            if (stager) pa = loadA(kt + 1);
            LOADB(n00, kt + 1, 0, 0); LOADB(n01, kt + 1, 0, 1);
            LOADB(n02, kt + 1, 0, 2); LOADB(n03, kt + 1, 0, 3);
            LOADB(n10, kt + 1, 1, 0); LOADB(n11, kt + 1, 1, 1);
            LOADB(n12, kt + 1, 1, 2); LOADB(n13, kt + 1, 1, 3);
        }
        bf16x8 af0 = *(const bf16x8*)(&As[cur][r15][g * 8]);
        acc[0] = __builtin_amdgcn_mfma_f32_16x16x32_bf16(af0, c00, acc[0], 0, 0, 0);
        acc[1] = __builtin_amdgcn_mfma_f32_16x16x32_bf16(af0, c01, acc[1], 0, 0, 0);
        acc[2] = __builtin_amdgcn_mfma_f32_16x16x32_bf16(af0, c02, acc[2], 0, 0, 0);
        acc[3] = __builtin_amdgcn_mfma_f32_16x16x32_bf16(af0, c03, acc[3], 0, 0, 0);
        bf16x8 af1 = *(const bf16x8*)(&As[cur][r15][32 + g * 8]);
        acc[0] = __builtin_amdgcn_mfma_f32_16x16x32_bf16(af1, c10, acc[0], 0, 0, 0);
        acc[1] = __builtin_amdgcn_mfma_f32_16x16x32_bf16(af1, c11, acc[1], 0, 0, 0);
        acc[2] = __builtin_amdgcn_mfma_f32_16x16x32_bf16(af1, c12, acc[2], 0, 0, 0);
        acc[3] = __builtin_amdgcn_mfma_f32_16x16x32_bf16(af1, c13, acc[3], 0, 0, 0);
        if (more) {
            if (stager) *(uint4*)(&As[cur ^ 1][ar][au * 8]) = pa;
            __syncthreads();
            c00 = n00; c01 = n01; c02 = n02; c03 = n03;
            c10 = n10; c11 = n11; c12 = n12; c13 = n13;
        }
    }
#undef LOADB

    float vals[4][4];
    float vs[4] = {0.f, 0.f, 0.f, 0.f}, vq[4] = {0.f, 0.f, 0.f, 0.f};
    #pragma unroll
    for (int tj = 0; tj < 4; ++tj) {
        int col = wave * 64 + tj * 16 + r15;
        float b = bias[col];
        #pragma unroll
        for (int r = 0; r < 4; ++r) {
            int row = g * 4 + r;
            float v = acc[tj][r] + b + resid[(size_t)pm[row] * 256 + col];
            vals[tj][r] = v;
            vs[r] += v; vq[r] += v * v;
        }
    }
    #pragma unroll
    for (int off = 1; off < 16; off <<= 1)
        #pragma unroll
        for (int r = 0; r < 4; ++r) {
            vs[r] += __shfl_xor(vs[r], off, 64);
            vq[r] += __shfl_xor(vq[r], off, 64);
        }
    if (r15 == 0) {
        #pragma unroll
        for (int r = 0; r < 4; ++r) { sW[wave][g * 4 + r] = vs[r]; qW[wave][g * 4 + r] = vq[r]; }
    }
    __syncthreads();
    if (tid < 16) {
        float s = sW[0][tid] + sW[1][tid] + sW[2][tid] + sW[3][tid];
        float q = qW[0][tid] + qW[1][tid] + qW[2][tid] + qW[3][tid];
        float mean = s * (1.0f / 256.0f);
        float var = q * (1.0f / 256.0f) - mean * mean;
        mS[tid] = mean;
        rS[tid] = rsqrtf(fmaxf(var, 0.f) + 1e-5f);
    }
    __syncthreads();

    #pragma unroll
    for (int tj = 0; tj < 4; ++tj) {
        int col = wave * 64 + tj * 16 + r15;
        float w = lnw[col], bb = lnb[col];
        #pragma unroll
        for (int r = 0; r < 4; ++r) {
            int row = g * 4 + r;
            float o = (vals[tj][r] - mS[row]) * rS[row] * w + bb;
            if constexpr (MODE == 0) {
                outf32[(size_t)(m0 + row) * 256 + col] = o;
                outbf[(size_t)(m0 + row) * 256 + col] = f2bf(o);
            } else if constexpr (MODE == 1) {
                outbf[(size_t)(m0 + row) * 256 + col] = f2bf(o);
            } else {
                int no = pm[row];
                bool ip = scores[no] > 0.5f;
                float qp = resid[(size_t)no * 256 + col];
                outf32[(size_t)no * 256 + col] = ip ? o : qp;
            }
        }
    }
}

// ---------------------------------------------------------------------------
// Group-sorted masked flash attention, swapped QK^T, max-free exp2 softmax.
// Key-split NSPLIT=4. (unchanged — proven)
// ---------------------------------------------------------------------------
__global__ __launch_bounds__(256) void k_attn(
    const unsigned short* __restrict__ QK, const unsigned short* __restrict__ Vt,
    const int* __restrict__ gid_s, const int* __restrict__ offs,
    float* __restrict__ Opart, float* __restrict__ lpart, int N)
{
    __shared__ __align__(16) unsigned short Ks[2][64][40];
    __shared__ __align__(16) unsigned short Vs[2][32][72];
    __shared__ __align__(16) unsigned short Ps[4][16][64];
    __shared__ __align__(16) int gks[2][64];

    int qtiles = N >> 6;
    int bid = blockIdx.x;
    int qt = bid % qtiles;
    int hs = bid / qtiles;
    int h = hs & 7;
    int sp = hs >> 3;
    int q0 = qt * 64;
    int tid = threadIdx.x, wave = tid >> 6, lane = tid & 63;
    int g = lane >> 4, r15 = lane & 15;
    int n0 = q0 + wave * 16;

    int g_lo = gid_s[q0], g_hi = gid_s[q0 + 63];
    int tlo = offs[g_lo] >> 6;
    int thi = (offs[g_hi + 1] + 63) >> 6;
    int ntiles = thi - tlo;
    int chunk = (ntiles + NSPLIT - 1) / NSPLIT;
    int t0 = tlo + sp * chunk;
    int t1 = min(t0 + chunk, thi);

    if (t0 >= t1) {
        #pragma unroll
        for (int r = 0; r < 4; ++r) {
            int n = n0 + g * 4 + r;
            Opart[((size_t)sp * N + n) * 256 + h * 32 + r15] = 0.f;
            Opart[((size_t)sp * N + n) * 256 + h * 32 + 16 + r15] = 0.f;
        }
        if (g == 0) lpart[((size_t)sp * N + n0 + r15) * 8 + h] = 0.f;
        return;
    }

    bf16x8 qf = *(const bf16x8*)(QK + (size_t)(n0 + r15) * 512 + h * 32 + g * 8);
    int gq = gid_s[n0 + r15];

    int kr_ = tid >> 2, kc_ = (tid & 3) * 8;
    int vd_ = tid >> 3, vc_ = (tid & 7) * 8;

    f32x4 O0 = {}, O1 = {};
    float lloc = 0.f;
    unsigned short* PsW = &Ps[wave][0][0];

    {
        int m0 = t0 << 6;
        *(uint4*)(&Ks[0][kr_][kc_]) = *(const uint4*)(QK + (size_t)(m0 + kr_) * 512 + 256 + h * 32 + kc_);
        *(uint4*)(&Vs[0][vd_][vc_]) = *(const uint4*)(Vt + (size_t)(h * 32 + vd_) * N + m0 + vc_);
        if (tid < 64) gks[0][tid] = gid_s[m0 + tid];
    }
    __syncthreads();

    int cur = 0;
    for (int t = t0; t < t1; ++t) {
        bool more = (t + 1 < t1);
        uint4 kn, vn; int gn = 0;
        if (more) {
            int m0n = (t + 1) << 6;
            kn = *(const uint4*)(QK + (size_t)(m0n + kr_) * 512 + 256 + h * 32 + kc_);
            vn = *(const uint4*)(Vt + (size_t)(h * 32 + vd_) * N + m0n + vc_);
            if (tid < 64) gn = gid_s[m0n + tid];
        }

        f32x4 S[4];
        #pragma unroll
        for (int t_ = 0; t_ < 4; ++t_) {
            bf16x8 kf = *(const bf16x8*)(&Ks[cur][t_ * 16 + r15][g * 8]);
            f32x4 z = {};
            S[t_] = __builtin_amdgcn_mfma_f32_16x16x32_bf16(kf, qf, z, 0, 0, 0);
        }
        #pragma unroll
        for (int t_ = 0; t_ < 4; ++t_) {
            int4 g4 = *(const int4*)(&gks[cur][t_ * 16 + g * 4]);
            float p0 = (g4.x == gq) ? exp2f(S[t_][0]) : 0.f;
            float p1 = (g4.y == gq) ? exp2f(S[t_][1]) : 0.f;
            float p2 = (g4.z == gq) ? exp2f(S[t_][2]) : 0.f;
            float p3 = (g4.w == gq) ? exp2f(S[t_][3]) : 0.f;
            lloc += (p0 + p1) + (p2 + p3);
            ushort4 pw;
            pw.x = f2bf(p0); pw.y = f2bf(p1); pw.z = f2bf(p2); pw.w = f2bf(p3);
            int off = t_ * 32 + g * 8;
            int byte = r15 * 128 + ((((off >> 4) ^ (r15 & 7)) << 4) | (off & 15));
            *(ushort4*)((char*)PsW + byte) = pw;
        }
        #pragma unroll
        for (int kk = 0; kk < 2; ++kk) {
            int byte = r15 * 128 + (((kk * 4 + g) ^ (r15 & 7)) << 4);
            bf16x8 pf = *(const bf16x8*)((char*)PsW + byte);
            bf16x8 v0 = *(const bf16x8*)(&Vs[cur][r15][kk * 32 + g * 8]);
            bf16x8 v1 = *(const bf16x8*)(&Vs[cur][16 + r15][kk * 32 + g * 8]);
            O0 = __builtin_amdgcn_mfma_f32_16x16x32_bf16(pf, v0, O0, 0, 0, 0);
            O1 = __builtin_amdgcn_mfma_f32_16x16x32_bf16(pf, v1, O1, 0, 0, 0);
        }

        if (more) {
            *(uint4*)(&Ks[cur ^ 1][kr_][kc_]) = kn;
            *(uint4*)(&Vs[cur ^ 1][vd_][vc_]) = vn;
            if (tid < 64) gks[cur ^ 1][tid] = gn;
        }
        __syncthreads();
        cur ^= 1;
    }

    float l = lloc;
    l += __shfl_xor(l, 16, 64);
    l += __shfl_xor(l, 32, 64);
    if (g == 0) lpart[((size_t)sp * N + n0 + r15) * 8 + h] = l;

    #pragma unroll
    for (int r = 0; r < 4; ++r) {
        int n = n0 + g * 4 + r;
        Opart[((size_t)sp * N + n) * 256 + h * 32 + r15]      = O0[r];
        Opart[((size_t)sp * N + n) * 256 + h * 32 + 16 + r15] = O1[r];
    }
}

// ---------------------------------------------------------------------------
extern "C" void kernel_launch(void* const* d_in, const int* in_sizes, int n_in,
                              void* d_out, int out_size, void* d_ws, size_t ws_size,
                              hipStream_t stream)
{
    const float* ref_pts    = (const float*)d_in[0];
    const float* pred_boxes = (const float*)d_in[1];
    const float* scores     = (const float*)d_in[2];
    const float* out_embed  = (const float*)d_in[3];
    const float* query_pos  = (const float*)d_in[4];
    const int*   group_ids  = (const int*)d_in[5];
    const float* in_proj_w  = (const float*)d_in[7];
    const float* in_proj_b  = (const float*)d_in[8];
    const float* out_proj_w = (const float*)d_in[9];
    const float* out_proj_b = (const float*)d_in[10];
    const float* lin1_w     = (const float*)d_in[11];
    const float* lin1_b     = (const float*)d_in[12];
    const float* lin2_w     = (const float*)d_in[13];
    const float* lin2_b     = (const float*)d_in[14];
    const float* feat1_w    = (const float*)d_in[15];
    const float* feat1_b    = (const float*)d_in[16];
    const float* feat2_w    = (const float*)d_in[17];
    const float* feat2_b    = (const float*)d_in[18];
    const float* norm1_w    = (const float*)d_in[19];
    const float* norm1_b    = (const float*)d_in[20];
    const float* norm2_w    = (const float*)d_in[21];
    const float* norm2_b    = (const float*)d_in[22];
    const float* normf_w    = (const float*)d_in[23];
    const float* normf_b    = (const float*)d_in[24];

    const int N = in_sizes[2];  // 4096

    char* ws = (char*)d_ws;
    size_t off = 0;
    auto alloc = [&](size_t bytes) -> void* {
        void* p = ws + off; off += (bytes + 255) & ~(size_t)255; return p;
    };
    unsigned short* wqkv   = (unsigned short*)alloc((size_t)768 * 256 * 2);
    unsigned short* wout   = (unsigned short*)alloc((size_t)256 * 256 * 2);
    unsigned short* wlin1  = (unsigned short*)alloc((size_t)1024 * 256 * 2);
    unsigned short* wlin2  = (unsigned short*)alloc((size_t)256 * 1024 * 2);
    unsigned short* wfeat1 = (unsigned short*)alloc((size_t)1024 * 256 * 2);
    unsigned short* wfeat2 = (unsigned short*)alloc((size_t)256 * 1024 * 2);
    unsigned short* qk_bf  = (unsigned short*)alloc((size_t)N * 256 * 2);
    unsigned short* emb_bf = (unsigned short*)alloc((size_t)N * 256 * 2);
    unsigned short* QKbuf  = (unsigned short*)alloc((size_t)N * 512 * 2);
    unsigned short* Vtbuf  = (unsigned short*)alloc((size_t)256 * N * 2);
    float*          tgtf   = (float*)alloc((size_t)N * 256 * 4);
    unsigned short* tgtbf  = (unsigned short*)alloc((size_t)N * 256 * 2);
    unsigned short* t2bf   = (unsigned short*)alloc((size_t)N * 256 * 2);
    unsigned short* hbuf   = (unsigned short*)alloc((size_t)N * 1024 * 2);
    int* permbuf = (int*)alloc((size_t)N * 4);
    int* gidsbuf = (int*)alloc((size_t)N * 4);
    int* offsbuf = (int*)alloc(32 * 4);
    float* Opartbuf = (float*)alloc((size_t)NSPLIT * N * 256 * 4);
    float* lbuf     = (float*)alloc((size_t)NSPLIT * N * 8 * 4);
    (void)ws_size; (void)n_in; (void)out_size;

    const int mt = N >> 6;

    // 1: weight conversion || group sort || prep (unsorted)
    k_setup<<<1345, 1024, 0, stream>>>(in_proj_w, out_proj_w, lin1_w, lin2_w, feat1_w, feat2_w,
                                       wqkv, wout, wlin1, wlin2, wfeat1, wfeat2,
                                       group_ids, N, permbuf, gidsbuf, offsbuf,
                                       ref_pts, pred_boxes, scores, out_embed,
                                       qk_bf, emb_bf);
    // 2: fused QKV projection (gathers A-rows via perm -> sorted outputs)
    k_gemm<EPI_QKV><<<mt * 12, 256, 0, stream>>>(
        qk_bf, emb_bf, wqkv, in_proj_b, permbuf, QKbuf, Vtbuf, N, 768, 256);
    // 3: key-split swapped-QK^T flash attention (NSPLIT=4)
    k_attn<<<mt * 8 * NSPLIT, 256, 0, stream>>>(QKbuf, Vtbuf, gidsbuf, offsbuf,
                                                Opartbuf, lbuf, N);
    // 4: out-proj (+combine, +residual out_embed[perm], +LN1) -> tgtf, tgtbf
    k_gemmln<256, 0><<<N / 16, 256, 0, stream>>>(
        nullptr, Opartbuf, lbuf, wout, out_proj_b, out_embed,
        norm1_w, norm1_b, tgtf, tgtbf, nullptr, permbuf, N);
    // 5: lin1 + relu -> hbuf
    k_gemm<EPI_RELUBF><<<mt * 16, 256, 0, stream>>>(
        tgtbf, nullptr, wlin1, lin1_b, nullptr, hbuf, nullptr, N, 1024, 256);
    // 6: lin2 (+residual tgtf, +LN2) -> t2bf
    k_gemmln<1024, 1><<<N / 16, 256, 0, stream>>>(
        hbuf, nullptr, nullptr, wlin2, lin2_b, tgtf,
        norm2_w, norm2_b, nullptr, t2bf, nullptr, permbuf, N);
    // 7: feat1 + relu -> hbuf
    k_gemm<EPI_RELUBF><<<mt * 16, 256, 0, stream>>>(
        t2bf, nullptr, wfeat1, feat1_b, nullptr, hbuf, nullptr, N, 1024, 256);
    // 8: feat2 (+residual query_pos[perm], +LNf, +select, +scatter) -> d_out
    k_gemmln<1024, 2><<<N / 16, 256, 0, stream>>>(
        hbuf, nullptr, nullptr, wfeat2, feat2_b, query_pos,
        normf_w, normf_b, (float*)d_out, nullptr, scores, permbuf, N);
}